// Round 3
// baseline (538.801 us; speedup 1.0000x reference)
//
#include <hip/hip_runtime.h>
#include <hip/hip_bf16.h>

#define D 128  // feature dim (D_IN == D_HID == 128)

typedef float f32x4 __attribute__((ext_vector_type(4)));
typedef __bf16 bf16x8 __attribute__((ext_vector_type(8)));

__device__ __forceinline__ unsigned short f2bf(float f) {
  unsigned int u = __float_as_uint(f);
  u += 0x7fff + ((u >> 16) & 1);  // RNE (no NaN inputs here)
  return (unsigned short)(u >> 16);
}

// async global->LDS, 16B per lane; LDS dest = wave-uniform base + lane*16
__device__ __forceinline__ void gl_lds16(const void* g, void* l) {
  __builtin_amdgcn_global_load_lds(
      (const __attribute__((address_space(1))) unsigned int*)g,
      (__attribute__((address_space(3))) unsigned int*)l, 16, 0, 0);
}

__device__ __forceinline__ int wave_incl_scan(int v, int lane) {
#pragma unroll
  for (int d = 1; d < 64; d <<= 1) {
    int t = __shfl_up(v, d);
    if (lane >= d) v += t;
  }
  return v;
}

// ---------------- CSR build (bucketed; no fine-grained global atomics) ----------------
#define NBK 196      // ceil(100000 / 512) buckets of 512 nodes
#define CHUNK 4096

// coarse bucket histogram: LDS-aggregated, 196 global atomics per block (hot lines)
__global__ __launch_bounds__(256) void k_bhist(const int* __restrict__ dst, int E,
                                               int* __restrict__ bcount) {
  __shared__ int cnt[NBK];
  const int tid = threadIdx.x;
  for (int i = tid; i < NBK; i += 256) cnt[i] = 0;
  __syncthreads();
  const int e0 = blockIdx.x * CHUNK;
  const int emax = min(e0 + CHUNK, E);
  for (int e = e0 + tid; e < emax; e += 256)
    atomicAdd(&cnt[((unsigned)dst[e]) >> 9], 1);
  __syncthreads();
  for (int i = tid; i < NBK; i += 256)
    if (cnt[i]) atomicAdd(&bcount[i], cnt[i]);
}

// pass A: scatter packed (src<<9 | dst&511) into bucket segments as contiguous runs.
// bucket_base scan is computed locally (redundant per block) -> k_bscan dispatch removed.
__global__ __launch_bounds__(256) void k_binA(const int* __restrict__ src,
                                              const int* __restrict__ dst, int E,
                                              const int* __restrict__ bcount,
                                              int* __restrict__ bcursor,
                                              int* __restrict__ pairbuf) {
  __shared__ int cnt[NBK];
  __shared__ int base[NBK];
  __shared__ int bb[NBK];  // local exclusive scan of bcount
  __shared__ int ws4[4];
  const int tid = threadIdx.x;
  const int e0 = blockIdx.x * CHUNK;
  const int emax = min(e0 + CHUNK, E);
  for (int i = tid; i < NBK; i += 256) cnt[i] = 0;
  {
    int lane = tid & 63, w = tid >> 6;
    int v = (tid < NBK) ? bcount[tid] : 0;
    int s = wave_incl_scan(v, lane);
    if (lane == 63) ws4[w] = s;
    __syncthreads();
    if (tid < NBK) {
      int off = 0;
      for (int k = 0; k < w; k++) off += ws4[k];
      bb[tid] = off + s - v;
    }
  }
  __syncthreads();
  for (int e = e0 + tid; e < emax; e += 256)
    atomicAdd(&cnt[((unsigned)dst[e]) >> 9], 1);
  __syncthreads();
  for (int i = tid; i < NBK; i += 256) {
    int c = cnt[i];
    int b = 0;
    if (c) b = atomicAdd(&bcursor[i], c) + bb[i];
    base[i] = b;
    cnt[i] = 0;
  }
  __syncthreads();
  for (int e = e0 + tid; e < emax; e += 256) {
    int d = dst[e];
    int bk = ((unsigned)d) >> 9;
    int pos = base[bk] + atomicAdd(&cnt[bk], 1);
    pairbuf[pos] = (src[e] << 9) | (d & 511);  // src<2^17, fits in 26 bits
  }
}

// pass B: one block owns one bucket. Computes its segment [start,end) from bcount
// locally (reduce), per-node degrees + local scan in LDS, writes row_ptr coalesced,
// scatters col inside LDS, dumps coalesced.
#define SEG_CAP 12800  // mean seg 8192, sigma ~91 -> cap is +50 sigma
__global__ __launch_bounds__(256) void k_binB(const int* __restrict__ pairbuf,
                                              const int* __restrict__ bcount,
                                              int* __restrict__ col,
                                              int* __restrict__ row_ptr, int N) {
  __shared__ int sdeg[512];
  __shared__ int rpl[512];  // local exclusive scan
  __shared__ int cur[512];
  __shared__ int wsum[4];
  __shared__ int wsum2[4];
  __shared__ int stage[SEG_CAP];
  const int tid = threadIdx.x;
  const int lane = tid & 63, wid = tid >> 6;
  const int node0 = blockIdx.x << 9;
  const int nn = min(512, N - node0);
  // start = sum_{i<bid} bcount[i]
  {
    int vv = (tid < (int)blockIdx.x) ? bcount[tid] : 0;
    vv += __shfl_down(vv, 32); vv += __shfl_down(vv, 16);
    vv += __shfl_down(vv, 8);  vv += __shfl_down(vv, 4);
    vv += __shfl_down(vv, 2);  vv += __shfl_down(vv, 1);
    if (lane == 0) wsum2[wid] = vv;
  }
  for (int i = tid; i < 512; i += 256) { sdeg[i] = 0; cur[i] = 0; }
  __syncthreads();
  const int start = wsum2[0] + wsum2[1] + wsum2[2] + wsum2[3];
  const int end = start + bcount[blockIdx.x];
  const int sz = end - start;  // <= SEG_CAP (astronomically certain)
  for (int i = tid; i < sz; i += 256)
    atomicAdd(&sdeg[pairbuf[start + i] & 511], 1);
  __syncthreads();
  // scan 512 degrees: thread t handles elements 2t, 2t+1
  int a = sdeg[2 * tid], b = sdeg[2 * tid + 1];
  int v = a + b;
  int s = wave_incl_scan(v, lane);
  if (lane == 63) wsum[wid] = s;
  __syncthreads();
  int off = 0;
  for (int k = 0; k < wid; k++) off += wsum[k];
  int e0l = off + s - v;
  rpl[2 * tid] = e0l;
  rpl[2 * tid + 1] = e0l + a;
  __syncthreads();
  // write row_ptr coalesced
  for (int i = tid; i < nn; i += 256) row_ptr[node0 + i] = start + rpl[i];
  if (blockIdx.x == gridDim.x - 1 && tid == 0) row_ptr[N] = end;
  // scatter into LDS stage, dump coalesced
  for (int i = tid; i < sz; i += 256) {
    int pk = pairbuf[start + i];  // coalesced read
    int d = pk & 511;
    int pos = rpl[d] + atomicAdd(&cur[d], 1);
    if (pos < SEG_CAP) stage[pos] = (int)(((unsigned)pk) >> 9);
  }
  __syncthreads();
  for (int i = tid; i < sz; i += 256) col[start + i] = stage[i];  // coalesced write
}

// ---- weight prep + workspace zeroing: Wt[n][k] bf16 from W[k][n] fp32 (6 mats),
// plus zero bcount/bcursor and the two gather-pad rows (folds 3 memsets away) ----
__global__ void k_prep(const float* __restrict__ W1, const float* __restrict__ W2,
                       unsigned short* __restrict__ Wt, int* __restrict__ bcount,
                       unsigned short* __restrict__ padA, unsigned short* __restrict__ padB) {
  int b = blockIdx.x;
  if (b < 6) {  // layer = b>>1, (b&1)==0 -> W1 else W2
    const float* W = (b & 1) ? (W2 + (size_t)(b >> 1) * D * D) : (W1 + (size_t)(b >> 1) * D * D);
    unsigned short* O = Wt + (size_t)b * D * D;
    for (int i = threadIdx.x; i < D * D; i += 256) {
      int n = i >> 7, k = i & 127;
      O[n * D + k] = f2bf(W[k * D + n]);  // writes coalesced; strided reads stay in L2
    }
  } else if (b == 6) {
    // bcount(256) + bcursor(256) contiguous: zero ALL 512 with a strided loop
    // (round-2 bug: single `if (tid<512)` with blockDim=256 left bcursor garbage
    //  -> k_binA atomicAdd from garbage -> OOB pairbuf writes -> device fault)
    for (int i = threadIdx.x; i < 512; i += 256) bcount[i] = 0;
  } else {
    if (threadIdx.x < 64) {
      ((unsigned int*)padA)[threadIdx.x] = 0u;
      ((unsigned int*)padB)[threadIdx.x] = 0u;
    }
  }
}

// ------------- MFMA GEMM: C[M,128] = A[M,128] @ W[128,128] (+bias)(+relu) -------------
// One 64-row tile per block, 256 threads = 4 waves (2x2), wave = 32 rows x 64 cols.
// LDS layout: row-major 256B rows, 16B chunks XOR-swizzled (physical p = logical ^ (row&15)).
template <bool A_FP32, bool OUT_FP32>
__global__ __launch_bounds__(256) void k_gemm(const void* __restrict__ Ain,
                                              const unsigned short* __restrict__ Wt,
                                              const float* __restrict__ bias,
                                              void* __restrict__ Cout, int M, int relu) {
  __shared__ __align__(16) unsigned short As[64 * 128];
  __shared__ __align__(16) unsigned short Bs[128 * 128];
  const int tid = threadIdx.x;
  const int wid = tid >> 6, lane = tid & 63;
  const int R0 = blockIdx.x * 64;

#pragma unroll
  for (int g = 0; g < 8; g++) {
    int flat = g * 256 + tid;
    int n = flat >> 4, p = flat & 15;
    int l = p ^ (n & 15);
    gl_lds16(Wt + (size_t)n * D + l * 8, &Bs[(size_t)(g * 256 + wid * 64) * 8]);
  }
  if (A_FP32) {
    const float* A = (const float*)Ain;
#pragma unroll
    for (int g = 0; g < 4; g++) {
      int flat = g * 256 + tid;
      int row = flat >> 4, p = flat & 15;
      int l = p ^ (row & 15);
      float4 a0 = make_float4(0.f, 0.f, 0.f, 0.f), a1 = a0;
      if (R0 + row < M) {
        a0 = *(const float4*)(A + (size_t)(R0 + row) * D + l * 8);
        a1 = *(const float4*)(A + (size_t)(R0 + row) * D + l * 8 + 4);
      }
      ushort4 v0, v1;
      v0.x = f2bf(a0.x); v0.y = f2bf(a0.y); v0.z = f2bf(a0.z); v0.w = f2bf(a0.w);
      v1.x = f2bf(a1.x); v1.y = f2bf(a1.y); v1.z = f2bf(a1.z); v1.w = f2bf(a1.w);
      *(ushort4*)&As[row * D + p * 8] = v0;
      *(ushort4*)&As[row * D + p * 8 + 4] = v1;
    }
  } else {
    const unsigned short* A = (const unsigned short*)Ain;
#pragma unroll
    for (int g = 0; g < 4; g++) {
      int flat = g * 256 + tid;
      int row = flat >> 4, p = flat & 15;
      int l = p ^ (row & 15);
      gl_lds16(A + (size_t)(R0 + row) * D + l * 8, &As[(size_t)(g * 256 + wid * 64) * 8]);
    }
  }
  __syncthreads();  // drains global_load_lds (vmcnt) + LDS writes

  const int wr = wid >> 1, wc = wid & 1;
  const int lm = lane & 15, lq = lane >> 4;
  f32x4 acc[2][4];
#pragma unroll
  for (int i = 0; i < 2; i++)
#pragma unroll
    for (int j = 0; j < 4; j++) acc[i][j] = f32x4{0.f, 0.f, 0.f, 0.f};

#pragma unroll
  for (int kc = 0; kc < 4; kc++) {
    const int pc = (kc * 4 + lq) ^ lm;
    bf16x8 af[2], bfr[4];
#pragma unroll
    for (int i = 0; i < 2; i++)
      af[i] = *(const bf16x8*)&As[(wr * 32 + i * 16 + lm) * D + pc * 8];
#pragma unroll
    for (int j = 0; j < 4; j++)
      bfr[j] = *(const bf16x8*)&Bs[(wc * 64 + j * 16 + lm) * D + pc * 8];
#pragma unroll
    for (int i = 0; i < 2; i++)
#pragma unroll
      for (int j = 0; j < 4; j++)
        acc[i][j] = __builtin_amdgcn_mfma_f32_16x16x32_bf16(af[i], bfr[j], acc[i][j], 0, 0, 0);
  }

  float bv[4];
#pragma unroll
  for (int j = 0; j < 4; j++) bv[j] = bias ? bias[wc * 64 + j * 16 + lm] : 0.f;
#pragma unroll
  for (int i = 0; i < 2; i++) {
#pragma unroll
    for (int reg = 0; reg < 4; reg++) {
      const int gr = R0 + wr * 32 + i * 16 + lq * 4 + reg;
      if (gr < M) {
#pragma unroll
        for (int j = 0; j < 4; j++) {
          const int gc = wc * 64 + j * 16 + lm;
          float v = acc[i][j][reg] + bv[j];
          if (relu) v = fmaxf(v, 0.f);
          if (OUT_FP32)
            ((float*)Cout)[(size_t)gr * D + gc] = v;
          else
            ((unsigned short*)Cout)[(size_t)gr * D + gc] = f2bf(v);
        }
      }
    }
  }
}

// ---- fused aggregate+GEMM(+GEMM): per block of 64 nodes,
//   As[r] = relu(Y[n] + sum_j Y[j] + b1)   (gathered straight into LDS, bf16, swizzled)
//   acc   = As @ Wa^T                       (the MLP's W2 GEMM)
//   FINAL:   store fp32  acc + b2
//   !FINAL:  As <- relu(acc + b2); store bf16 (As @ Wb^T)   (next layer's W1, LDS bounce)
// Removes the agg H-write + GEMM A-re-read (50MB/boundary) and one dispatch each.
// Gather pipeline: one wave per node PAIR, 16-deep in flight (throughput-bound).
#define ISSUE8(vv, cvh, base)                              \
  _Pragma("unroll") for (int u = 0; u < 8; u++) {          \
    int s_ = __shfl((cvh), (base) + u);                    \
    vv[u] = Yu[(size_t)s_ * 64 + lane];                    \
  }

#define REDUCE8(vv, jb)                                    \
  _Pragma("unroll") for (int u = 0; u < 8; u++) {          \
    float fx_ = __uint_as_float(vv[u] << 16);              \
    float fy_ = __uint_as_float(vv[u] & 0xffff0000u);      \
    if ((jb) + u < degA) { axA += fx_; ayA += fy_; }       \
    else { axB += fx_; ayB += fy_; }                       \
  }

template <bool FINAL>
__global__ __launch_bounds__(256) void k_aggemm(
    const unsigned short* __restrict__ Y, const int* __restrict__ row_ptr,
    const int* __restrict__ col, const float* __restrict__ b1,
    const unsigned short* __restrict__ Wa, const unsigned short* __restrict__ Wb,
    const float* __restrict__ b2, void* __restrict__ Cout, int N) {
  __shared__ __align__(16) unsigned short As[64 * 128];
  __shared__ __align__(16) unsigned short Bs[128 * 128];
  const int tid = threadIdx.x;
  const int wid = tid >> 6, lane = tid & 63;
  const int R0 = blockIdx.x * 64;

  // stage Wa into Bs (async; drained by the pre-MFMA barrier, hides under gathers)
#pragma unroll
  for (int g = 0; g < 8; g++) {
    int flat = g * 256 + tid;
    int n = flat >> 4, p = flat & 15;
    int l = p ^ (n & 15);
    gl_lds16(Wa + (size_t)n * D + l * 8, &Bs[(size_t)(g * 256 + wid * 64) * 8]);
  }

  const unsigned int* Yu = (const unsigned int*)Y;
  unsigned int* Asu = (unsigned int*)As;
  const float2 bv = ((const float2*)b1)[lane];

  // ---- gather phase: 8 pairs (16 node rows) per wave ----
  for (int pi = 0; pi < 8; pi++) {
    const int r0 = wid * 16 + pi * 2;  // local row of nA (wave-uniform)
    const int nA = R0 + r0, nB = nA + 1;
    // As write addrs: lane holds channels (2l,2l+1); chunk c8=l>>2, phys = c8^(row&15)
    const int wA = r0 * 64 + (((lane >> 2) ^ (r0 & 15)) << 2) + (lane & 3);
    const int wB = (r0 + 1) * 64 + (((lane >> 2) ^ ((r0 + 1) & 15)) << 2) + (lane & 3);
    if (nA >= N) { Asu[wA] = 0u; Asu[wB] = 0u; continue; }
    const bool hasB = (nB < N);
    unsigned int svA = Yu[(size_t)nA * 64 + lane];
    unsigned int svB = hasB ? Yu[(size_t)nB * 64 + lane] : 0u;
    int rsA = row_ptr[nA];
    int reA = row_ptr[nA + 1];
    int reB = hasB ? row_ptr[nA + 2] : reA;
    rsA = __builtin_amdgcn_readfirstlane(rsA);
    reA = __builtin_amdgcn_readfirstlane(reA);
    reB = __builtin_amdgcn_readfirstlane(reB);
    const int degA = min(reA - rsA, 64);
    const int degB = min(reB - reA, 64);
    const int m = degA + degB;
    const int nb = (m + 7) >> 3;

    float axA = bv.x + __uint_as_float(svA << 16);
    float ayA = bv.y + __uint_as_float(svA & 0xffff0000u);
    float axB = bv.x + __uint_as_float(svB << 16);
    float ayB = bv.y + __uint_as_float(svB & 0xffff0000u);

    // merged neighbor list (contiguous in CSR); pad gathers hit the zero row at N
    int cv0 = N, cv1 = N;
    if (lane < degA) cv0 = col[rsA + lane];
    else if (lane - degA < degB) cv0 = col[reA + (lane - degA)];
    if (64 + lane < m) cv1 = col[reA + (64 + lane - degA)];

    unsigned int g0[8], g1[8];
    int issued = 0, done = 0;
    if (nb > 0) { ISSUE8(g0, cv0, 0); issued = 1; }
    if (nb > 1) { ISSUE8(g1, cv0, 8); issued = 2; }
    while (done < nb) {
      if ((done & 1) == 0) { REDUCE8(g0, (done << 3)); }
      else { REDUCE8(g1, (done << 3)); }
      done++;
      if (issued < nb) {
        int ch = (issued < 8) ? cv0 : cv1;
        int bs = (issued & 7) << 3;
        if ((issued & 1) == 0) { ISSUE8(g0, ch, bs); }
        else { ISSUE8(g1, ch, bs); }
        issued++;
      }
    }
    // deg>64 never happens statistically; correctness net
    for (int t = rsA + 64; t < reA; t++) {
      unsigned int v = Yu[(size_t)col[t] * 64 + lane];
      axA += __uint_as_float(v << 16);
      ayA += __uint_as_float(v & 0xffff0000u);
    }
    for (int t = reA + 64; t < reB; t++) {
      unsigned int v = Yu[(size_t)col[t] * 64 + lane];
      axB += __uint_as_float(v << 16);
      ayB += __uint_as_float(v & 0xffff0000u);
    }
    Asu[wA] = ((unsigned int)f2bf(fmaxf(ayA, 0.f)) << 16) | f2bf(fmaxf(axA, 0.f));
    Asu[wB] = hasB ? (((unsigned int)f2bf(fmaxf(ayB, 0.f)) << 16) | f2bf(fmaxf(axB, 0.f)))
                   : 0u;
  }
  __syncthreads();  // drains Wa gl_lds (vmcnt) + As ds_writes

  // ---- MFMA stage 1: acc = As @ Wa^T ----
  const int wr = wid >> 1, wc = wid & 1;
  const int lm = lane & 15, lq = lane >> 4;
  f32x4 acc[2][4];
#pragma unroll
  for (int i = 0; i < 2; i++)
#pragma unroll
    for (int j = 0; j < 4; j++) acc[i][j] = f32x4{0.f, 0.f, 0.f, 0.f};
#pragma unroll
  for (int kc = 0; kc < 4; kc++) {
    const int pc = (kc * 4 + lq) ^ lm;
    bf16x8 af[2], bfr[4];
#pragma unroll
    for (int i = 0; i < 2; i++)
      af[i] = *(const bf16x8*)&As[(wr * 32 + i * 16 + lm) * D + pc * 8];
#pragma unroll
    for (int j = 0; j < 4; j++)
      bfr[j] = *(const bf16x8*)&Bs[(wc * 64 + j * 16 + lm) * D + pc * 8];
#pragma unroll
    for (int i = 0; i < 2; i++)
#pragma unroll
      for (int j = 0; j < 4; j++)
        acc[i][j] = __builtin_amdgcn_mfma_f32_16x16x32_bf16(af[i], bfr[j], acc[i][j], 0, 0, 0);
  }

  if (FINAL) {
    // epilogue: +b2, fp32 out
    float bvv[4];
#pragma unroll
    for (int j = 0; j < 4; j++) bvv[j] = b2[wc * 64 + j * 16 + lm];
#pragma unroll
    for (int i = 0; i < 2; i++) {
#pragma unroll
      for (int reg = 0; reg < 4; reg++) {
        const int gr = R0 + wr * 32 + i * 16 + lq * 4 + reg;
        if (gr < N) {
#pragma unroll
          for (int j = 0; j < 4; j++) {
            const int gc = wc * 64 + j * 16 + lm;
            ((float*)Cout)[(size_t)gr * D + gc] = acc[i][j][reg] + bvv[j];
          }
        }
      }
    }
  } else {
    __syncthreads();  // all waves done reading As & Bs
    // re-stage Bs <- Wb (in flight across epilogue1; drained by next barrier)
#pragma unroll
    for (int g = 0; g < 8; g++) {
      int flat = g * 256 + tid;
      int n = flat >> 4, p = flat & 15;
      int l = p ^ (n & 15);
      gl_lds16(Wb + (size_t)n * D + l * 8, &Bs[(size_t)(g * 256 + wid * 64) * 8]);
    }
    // epilogue1: X = relu(acc + b2) -> bf16 into As (same XOR-swizzled layout)
    {
      float bvv[4];
#pragma unroll
      for (int j = 0; j < 4; j++) bvv[j] = b2[wc * 64 + j * 16 + lm];
#pragma unroll
      for (int i = 0; i < 2; i++) {
#pragma unroll
        for (int reg = 0; reg < 4; reg++) {
          const int row = wr * 32 + i * 16 + lq * 4 + reg;
#pragma unroll
          for (int j = 0; j < 4; j++) {
            const int gc = wc * 64 + j * 16 + lm;
            float v = fmaxf(acc[i][j][reg] + bvv[j], 0.f);
            As[row * D + (((gc >> 3) ^ (row & 15)) << 3) + (gc & 7)] = f2bf(v);
          }
        }
      }
    }
    __syncthreads();  // drains gl_lds (vmcnt) + ds_writes

    f32x4 acc2[2][4];
#pragma unroll
    for (int i = 0; i < 2; i++)
#pragma unroll
      for (int j = 0; j < 4; j++) acc2[i][j] = f32x4{0.f, 0.f, 0.f, 0.f};
#pragma unroll
    for (int kc = 0; kc < 4; kc++) {
      const int pc = (kc * 4 + lq) ^ lm;
      bf16x8 af[2], bfr[4];
#pragma unroll
      for (int i = 0; i < 2; i++)
        af[i] = *(const bf16x8*)&As[(wr * 32 + i * 16 + lm) * D + pc * 8];
#pragma unroll
      for (int j = 0; j < 4; j++)
        bfr[j] = *(const bf16x8*)&Bs[(wc * 64 + j * 16 + lm) * D + pc * 8];
#pragma unroll
      for (int i = 0; i < 2; i++)
#pragma unroll
        for (int j = 0; j < 4; j++)
          acc2[i][j] = __builtin_amdgcn_mfma_f32_16x16x32_bf16(af[i], bfr[j], acc2[i][j], 0, 0, 0);
    }
    // epilogue2: Y' bf16 to global (no bias, no relu)
#pragma unroll
    for (int i = 0; i < 2; i++) {
#pragma unroll
      for (int reg = 0; reg < 4; reg++) {
        const int gr = R0 + wr * 32 + i * 16 + lq * 4 + reg;
        if (gr < N) {
#pragma unroll
          for (int j = 0; j < 4; j++) {
            const int gc = wc * 64 + j * 16 + lm;
            ((unsigned short*)Cout)[(size_t)gr * D + gc] = f2bf(acc2[i][j][reg]);
          }
        }
      }
    }
  }
}

// ---------------- launch ----------------
// GIN eps=0: out = MLP(x + sum_src x). Linearity: GEMM(W1) first, then fused
// aggregate(+b1,relu)+GEMM(W2)(+relu+b2 bounce+GEMM(W1_next)). 8 dispatches total.
extern "C" void kernel_launch(void* const* d_in, const int* in_sizes, int n_in,
                              void* d_out, int out_size, void* d_ws, size_t ws_size,
                              hipStream_t stream) {
  const float* x  = (const float*)d_in[0];
  const int*   ei = (const int*)d_in[1];
  const float* W1 = (const float*)d_in[2];
  const float* b1 = (const float*)d_in[3];
  const float* W2 = (const float*)d_in[4];
  const float* b2 = (const float*)d_in[5];
  const int N = in_sizes[0] / D;  // 100000
  const int E = in_sizes[1] / 2;  // 1600000
  const int* src = ei;
  const int* dst = ei + E;

  // workspace: Wt (192KB) + 2 bf16 node buffers of (N+1) rows (row N = zero pad,
  // gather-pad target) + CSR (~7MB). pairbuf aliases bufB (dead before bufB written;
  // 6.4MB < 25.6MB so pad rows survive).
  char* ws = (char*)d_ws;
  unsigned short* Wt   = (unsigned short*)ws;                 // 6*128*128 bf16
  unsigned short* bufA = Wt + 6 * D * D;
  unsigned short* bufB = bufA + (size_t)(N + 1) * D;
  int* pairbuf = (int*)bufB;
  int* row_ptr = (int*)(bufB + (size_t)(N + 1) * D);
  int* colv    = row_ptr + (N + 1);
  int* bcount  = colv + E;          // 256 ints
  int* bcursor = bcount + 256;      // 256 ints (must follow bcount: zeroed together)
  float* OUT   = (float*)d_out;

  const int CB = (E + CHUNK - 1) / CHUNK;      // 391 chunk blocks
  const int GB = (N + 63) / 64;                // 1563 tiles
  const int BKB = (N + 511) / 512;             // 196 buckets

  k_prep<<<8, 256, 0, stream>>>(W1, W2, Wt, bcount,
                                bufA + (size_t)N * D, bufB + (size_t)N * D);
  k_bhist<<<CB, 256, 0, stream>>>(dst, E, bcount);
  k_binA<<<CB, 256, 0, stream>>>(src, dst, E, bcount, bcursor, pairbuf);
  k_binB<<<BKB, 256, 0, stream>>>(pairbuf, bcount, colv, row_ptr, N);

  // layer 0 front GEMM: Y0 = x @ W1_0
  k_gemm<true, false><<<GB, 256, 0, stream>>>(x, Wt + 0 * D * D, nullptr, bufA, N, 0);
  // fused: agg(Y0)+b1_0,relu -> @W2_0 -> relu(+b2_0) -> @W1_1 -> Y1
  k_aggemm<false><<<GB, 256, 0, stream>>>(bufA, row_ptr, colv, b1,
                                          Wt + 1 * D * D, Wt + 2 * D * D, b2, bufB, N);
  // fused: agg(Y1)+b1_1,relu -> @W2_1 -> relu(+b2_1) -> @W1_2 -> Y2
  k_aggemm<false><<<GB, 256, 0, stream>>>(bufB, row_ptr, colv, b1 + D,
                                          Wt + 3 * D * D, Wt + 4 * D * D, b2 + D, bufA, N);
  // fused final: agg(Y2)+b1_2,relu -> @W2_2 + b2_2 -> fp32 OUT
  k_aggemm<true><<<GB, 256, 0, stream>>>(bufA, row_ptr, colv, b1 + 2 * D,
                                         Wt + 5 * D * D, nullptr, b2 + 2 * D, OUT, N);
  (void)n_in; (void)out_size; (void)ws_size;
}

// Round 4
// 420.609 us; speedup vs baseline: 1.2810x; 1.2810x over previous
//
#include <hip/hip_runtime.h>
#include <hip/hip_bf16.h>

#define D 128  // feature dim (D_IN == D_HID == 128)

typedef float f32x4 __attribute__((ext_vector_type(4)));
typedef __bf16 bf16x8 __attribute__((ext_vector_type(8)));

__device__ __forceinline__ unsigned short f2bf(float f) {
  unsigned int u = __float_as_uint(f);
  u += 0x7fff + ((u >> 16) & 1);  // RNE (no NaN inputs here)
  return (unsigned short)(u >> 16);
}

// async global->LDS, 16B per lane; LDS dest = wave-uniform base + lane*16
__device__ __forceinline__ void gl_lds16(const void* g, void* l) {
  __builtin_amdgcn_global_load_lds(
      (const __attribute__((address_space(1))) unsigned int*)g,
      (__attribute__((address_space(3))) unsigned int*)l, 16, 0, 0);
}

__device__ __forceinline__ int wave_incl_scan(int v, int lane) {
#pragma unroll
  for (int d = 1; d < 64; d <<= 1) {
    int t = __shfl_up(v, d);
    if (lane >= d) v += t;
  }
  return v;
}

// ---------------- CSR build (bucketed; no fine-grained global atomics) ----------------
#define NBK 196      // ceil(100000 / 512) buckets of 512 nodes
#define CHUNK 4096

// coarse bucket histogram: LDS-aggregated, 196 global atomics per block (hot lines)
__global__ __launch_bounds__(256) void k_bhist(const int* __restrict__ dst, int E,
                                               int* __restrict__ bcount) {
  __shared__ int cnt[NBK];
  const int tid = threadIdx.x;
  for (int i = tid; i < NBK; i += 256) cnt[i] = 0;
  __syncthreads();
  const int e0 = blockIdx.x * CHUNK;
  const int emax = min(e0 + CHUNK, E);
  for (int e = e0 + tid; e < emax; e += 256)
    atomicAdd(&cnt[((unsigned)dst[e]) >> 9], 1);
  __syncthreads();
  for (int i = tid; i < NBK; i += 256)
    if (cnt[i]) atomicAdd(&bcount[i], cnt[i]);
}

// pass A: scatter packed (src<<9 | dst&511) into bucket segments as contiguous runs.
// bucket_base scan computed locally per block (k_bscan dispatch stays removed).
__global__ __launch_bounds__(256) void k_binA(const int* __restrict__ src,
                                              const int* __restrict__ dst, int E,
                                              const int* __restrict__ bcount,
                                              int* __restrict__ bcursor,
                                              int* __restrict__ pairbuf) {
  __shared__ int cnt[NBK];
  __shared__ int base[NBK];
  __shared__ int bb[NBK];  // local exclusive scan of bcount
  __shared__ int ws4[4];
  const int tid = threadIdx.x;
  const int e0 = blockIdx.x * CHUNK;
  const int emax = min(e0 + CHUNK, E);
  for (int i = tid; i < NBK; i += 256) cnt[i] = 0;
  {
    int lane = tid & 63, w = tid >> 6;
    int v = (tid < NBK) ? bcount[tid] : 0;
    int s = wave_incl_scan(v, lane);
    if (lane == 63) ws4[w] = s;
    __syncthreads();
    if (tid < NBK) {
      int off = 0;
      for (int k = 0; k < w; k++) off += ws4[k];
      bb[tid] = off + s - v;
    }
  }
  __syncthreads();
  for (int e = e0 + tid; e < emax; e += 256)
    atomicAdd(&cnt[((unsigned)dst[e]) >> 9], 1);
  __syncthreads();
  for (int i = tid; i < NBK; i += 256) {
    int c = cnt[i];
    int b = 0;
    if (c) b = atomicAdd(&bcursor[i], c) + bb[i];
    base[i] = b;
    cnt[i] = 0;
  }
  __syncthreads();
  for (int e = e0 + tid; e < emax; e += 256) {
    int d = dst[e];
    int bk = ((unsigned)d) >> 9;
    int pos = base[bk] + atomicAdd(&cnt[bk], 1);
    pairbuf[pos] = (src[e] << 9) | (d & 511);  // src<2^17, fits in 26 bits
  }
}

// pass B: one block owns one bucket. Computes its segment [start,end) from bcount
// locally (reduce), per-node degrees + local scan in LDS, writes row_ptr coalesced,
// scatters col inside LDS, dumps coalesced.
#define SEG_CAP 12800  // mean seg 8192, sigma ~91 -> cap is +50 sigma
__global__ __launch_bounds__(256) void k_binB(const int* __restrict__ pairbuf,
                                              const int* __restrict__ bcount,
                                              int* __restrict__ col,
                                              int* __restrict__ row_ptr, int N) {
  __shared__ int sdeg[512];
  __shared__ int rpl[512];  // local exclusive scan
  __shared__ int cur[512];
  __shared__ int wsum[4];
  __shared__ int wsum2[4];
  __shared__ int stage[SEG_CAP];
  const int tid = threadIdx.x;
  const int lane = tid & 63, wid = tid >> 6;
  const int node0 = blockIdx.x << 9;
  const int nn = min(512, N - node0);
  // start = sum_{i<bid} bcount[i]
  {
    int vv = (tid < (int)blockIdx.x) ? bcount[tid] : 0;
    vv += __shfl_down(vv, 32); vv += __shfl_down(vv, 16);
    vv += __shfl_down(vv, 8);  vv += __shfl_down(vv, 4);
    vv += __shfl_down(vv, 2);  vv += __shfl_down(vv, 1);
    if (lane == 0) wsum2[wid] = vv;
  }
  for (int i = tid; i < 512; i += 256) { sdeg[i] = 0; cur[i] = 0; }
  __syncthreads();
  const int start = wsum2[0] + wsum2[1] + wsum2[2] + wsum2[3];
  const int end = start + bcount[blockIdx.x];
  const int sz = end - start;  // <= SEG_CAP (astronomically certain)
  for (int i = tid; i < sz; i += 256)
    atomicAdd(&sdeg[pairbuf[start + i] & 511], 1);
  __syncthreads();
  // scan 512 degrees: thread t handles elements 2t, 2t+1
  int a = sdeg[2 * tid], b = sdeg[2 * tid + 1];
  int v = a + b;
  int s = wave_incl_scan(v, lane);
  if (lane == 63) wsum[wid] = s;
  __syncthreads();
  int off = 0;
  for (int k = 0; k < wid; k++) off += wsum[k];
  int e0l = off + s - v;
  rpl[2 * tid] = e0l;
  rpl[2 * tid + 1] = e0l + a;
  __syncthreads();
  // write row_ptr coalesced
  for (int i = tid; i < nn; i += 256) row_ptr[node0 + i] = start + rpl[i];
  if (blockIdx.x == gridDim.x - 1 && tid == 0) row_ptr[N] = end;
  // scatter into LDS stage, dump coalesced
  for (int i = tid; i < sz; i += 256) {
    int pk = pairbuf[start + i];  // coalesced read
    int d = pk & 511;
    int pos = rpl[d] + atomicAdd(&cur[d], 1);
    if (pos < SEG_CAP) stage[pos] = (int)(((unsigned)pk) >> 9);
  }
  __syncthreads();
  for (int i = tid; i < sz; i += 256) col[start + i] = stage[i];  // coalesced write
}

// ---- weight prep + workspace zeroing: Wt[n][k] bf16 from W[k][n] fp32 (6 mats),
// plus zero bcount/bcursor (strided loop — round-2 lesson: blockDim=256!) ----
__global__ void k_prep(const float* __restrict__ W1, const float* __restrict__ W2,
                       unsigned short* __restrict__ Wt, int* __restrict__ bcount) {
  int b = blockIdx.x;
  if (b < 6) {  // layer = b>>1, (b&1)==0 -> W1 else W2
    const float* W = (b & 1) ? (W2 + (size_t)(b >> 1) * D * D) : (W1 + (size_t)(b >> 1) * D * D);
    unsigned short* O = Wt + (size_t)b * D * D;
    for (int i = threadIdx.x; i < D * D; i += 256) {
      int n = i >> 7, k = i & 127;
      O[n * D + k] = f2bf(W[k * D + n]);  // writes coalesced; strided reads stay in L2
    }
  } else {
    for (int i = threadIdx.x; i < 512; i += 256) bcount[i] = 0;  // bcount+bcursor
  }
}

// ------------- aggregation (bf16 in/out): H[i] = relu(Y[i] + sum_j Y[j] + b) -------------
// one wave per node (v1 body — measured 62.7us, VGPR 20, Occ 67%; concurrency-limited
// random-gather ceiling ~3.46 TB/s counted at TCC. Round-3 lesson: do NOT co-locate
// with MFMA tiles — gather throughput scales with resident waves).
__global__ __launch_bounds__(256) void k_agg(const unsigned short* __restrict__ Y,
                                             const int* __restrict__ row_ptr,
                                             const int* __restrict__ col,
                                             const float* __restrict__ bias,
                                             unsigned short* __restrict__ H, int N) {
  int wid = (blockIdx.x * 256 + threadIdx.x) >> 6;  // node
  int lane = threadIdx.x & 63;
  if (wid >= N) return;
  const unsigned int* Yu = (const unsigned int*)Y;
  unsigned int sv = Yu[(size_t)wid * 64 + lane];
  float2 bv = ((const float2*)bias)[lane];
  float ax = bv.x + __uint_as_float(sv << 16);
  float ay = bv.y + __uint_as_float(sv & 0xffff0000u);
  int rs = row_ptr[wid], re = row_ptr[wid + 1];
  int deg = re - rs;
  int dcap = min(deg, 64);
  int cv = (lane < dcap) ? col[rs + lane] : 0;  // one coalesced read of the whole list
  int j = 0;
  for (; j + 8 <= dcap; j += 8) {
    int s0 = __shfl(cv, j + 0), s1 = __shfl(cv, j + 1);
    int s2 = __shfl(cv, j + 2), s3 = __shfl(cv, j + 3);
    int s4 = __shfl(cv, j + 4), s5 = __shfl(cv, j + 5);
    int s6 = __shfl(cv, j + 6), s7 = __shfl(cv, j + 7);
    unsigned int v0 = Yu[(size_t)s0 * 64 + lane];
    unsigned int v1 = Yu[(size_t)s1 * 64 + lane];
    unsigned int v2 = Yu[(size_t)s2 * 64 + lane];
    unsigned int v3 = Yu[(size_t)s3 * 64 + lane];
    unsigned int v4 = Yu[(size_t)s4 * 64 + lane];
    unsigned int v5 = Yu[(size_t)s5 * 64 + lane];
    unsigned int v6 = Yu[(size_t)s6 * 64 + lane];
    unsigned int v7 = Yu[(size_t)s7 * 64 + lane];
    ax += ((__uint_as_float(v0 << 16) + __uint_as_float(v1 << 16)) +
           (__uint_as_float(v2 << 16) + __uint_as_float(v3 << 16))) +
          ((__uint_as_float(v4 << 16) + __uint_as_float(v5 << 16)) +
           (__uint_as_float(v6 << 16) + __uint_as_float(v7 << 16)));
    ay += ((__uint_as_float(v0 & 0xffff0000u) + __uint_as_float(v1 & 0xffff0000u)) +
           (__uint_as_float(v2 & 0xffff0000u) + __uint_as_float(v3 & 0xffff0000u))) +
          ((__uint_as_float(v4 & 0xffff0000u) + __uint_as_float(v5 & 0xffff0000u)) +
           (__uint_as_float(v6 & 0xffff0000u) + __uint_as_float(v7 & 0xffff0000u)));
  }
  for (; j < dcap; j++) {
    int s = __shfl(cv, j);
    unsigned int v = Yu[(size_t)s * 64 + lane];
    ax += __uint_as_float(v << 16);
    ay += __uint_as_float(v & 0xffff0000u);
  }
  for (int t = rs + 64; t < re; t++) {  // deg>64 never happens statistically; correctness net
    unsigned int v = Yu[(size_t)col[t] * 64 + lane];
    ax += __uint_as_float(v << 16);
    ay += __uint_as_float(v & 0xffff0000u);
  }
  ax = fmaxf(ax, 0.f);
  ay = fmaxf(ay, 0.f);
  unsigned int packed = ((unsigned int)f2bf(ay) << 16) | f2bf(ax);
  ((unsigned int*)H)[(size_t)wid * 64 + lane] = packed;
}

// ------------- MFMA GEMM: C[M,128] = A[M,128] @ W[128,128] (+bias)(+relu) -------------
// One 64-row tile per block, 256 threads = 4 waves (2x2), wave = 32 rows x 64 cols.
// LDS layout: row-major 256B rows, 16B chunks XOR-swizzled (physical p = logical ^ (row&15)).
template <bool A_FP32, bool OUT_FP32>
__global__ __launch_bounds__(256) void k_gemm(const void* __restrict__ Ain,
                                              const unsigned short* __restrict__ Wt,
                                              const float* __restrict__ bias,
                                              void* __restrict__ Cout, int M, int relu) {
  __shared__ __align__(16) unsigned short As[64 * 128];
  __shared__ __align__(16) unsigned short Bs[128 * 128];
  const int tid = threadIdx.x;
  const int wid = tid >> 6, lane = tid & 63;
  const int R0 = blockIdx.x * 64;

#pragma unroll
  for (int g = 0; g < 8; g++) {
    int flat = g * 256 + tid;
    int n = flat >> 4, p = flat & 15;
    int l = p ^ (n & 15);
    gl_lds16(Wt + (size_t)n * D + l * 8, &Bs[(size_t)(g * 256 + wid * 64) * 8]);
  }
  if (A_FP32) {
    const float* A = (const float*)Ain;
#pragma unroll
    for (int g = 0; g < 4; g++) {
      int flat = g * 256 + tid;
      int row = flat >> 4, p = flat & 15;
      int l = p ^ (row & 15);
      float4 a0 = make_float4(0.f, 0.f, 0.f, 0.f), a1 = a0;
      if (R0 + row < M) {
        a0 = *(const float4*)(A + (size_t)(R0 + row) * D + l * 8);
        a1 = *(const float4*)(A + (size_t)(R0 + row) * D + l * 8 + 4);
      }
      ushort4 v0, v1;
      v0.x = f2bf(a0.x); v0.y = f2bf(a0.y); v0.z = f2bf(a0.z); v0.w = f2bf(a0.w);
      v1.x = f2bf(a1.x); v1.y = f2bf(a1.y); v1.z = f2bf(a1.z); v1.w = f2bf(a1.w);
      *(ushort4*)&As[row * D + p * 8] = v0;
      *(ushort4*)&As[row * D + p * 8 + 4] = v1;
    }
  } else {
    const unsigned short* A = (const unsigned short*)Ain;
#pragma unroll
    for (int g = 0; g < 4; g++) {
      int flat = g * 256 + tid;
      int row = flat >> 4, p = flat & 15;
      int l = p ^ (row & 15);
      // rows >= M read garbage from adjacent ws buffers (safe); their outputs unstored
      gl_lds16(A + (size_t)(R0 + row) * D + l * 8, &As[(size_t)(g * 256 + wid * 64) * 8]);
    }
  }
  __syncthreads();  // drains global_load_lds (vmcnt) + LDS writes

  const int wr = wid >> 1, wc = wid & 1;
  const int lm = lane & 15, lq = lane >> 4;
  f32x4 acc[2][4];
#pragma unroll
  for (int i = 0; i < 2; i++)
#pragma unroll
    for (int j = 0; j < 4; j++) acc[i][j] = f32x4{0.f, 0.f, 0.f, 0.f};

#pragma unroll
  for (int kc = 0; kc < 4; kc++) {
    const int pc = (kc * 4 + lq) ^ lm;
    bf16x8 af[2], bfr[4];
#pragma unroll
    for (int i = 0; i < 2; i++)
      af[i] = *(const bf16x8*)&As[(wr * 32 + i * 16 + lm) * D + pc * 8];
#pragma unroll
    for (int j = 0; j < 4; j++)
      bfr[j] = *(const bf16x8*)&Bs[(wc * 64 + j * 16 + lm) * D + pc * 8];
#pragma unroll
    for (int i = 0; i < 2; i++)
#pragma unroll
      for (int j = 0; j < 4; j++)
        acc[i][j] = __builtin_amdgcn_mfma_f32_16x16x32_bf16(af[i], bfr[j], acc[i][j], 0, 0, 0);
  }

  float bv[4];
#pragma unroll
  for (int j = 0; j < 4; j++) bv[j] = bias ? bias[wc * 64 + j * 16 + lm] : 0.f;
#pragma unroll
  for (int i = 0; i < 2; i++) {
#pragma unroll
    for (int reg = 0; reg < 4; reg++) {
      const int gr = R0 + wr * 32 + i * 16 + lq * 4 + reg;
      if (gr < M) {
#pragma unroll
        for (int j = 0; j < 4; j++) {
          const int gc = wc * 64 + j * 16 + lm;
          float v = acc[i][j][reg] + bv[j];
          if (relu) v = fmaxf(v, 0.f);
          if (OUT_FP32)
            ((float*)Cout)[(size_t)gr * D + gc] = v;
          else
            ((unsigned short*)Cout)[(size_t)gr * D + gc] = f2bf(v);
        }
      }
    }
  }
}

// ---- fused GEMM pair: C = relu(A@W2t^T + b2) @ W1t^T, all bf16 in/out ----
// Stage1 result bounces through LDS (As reused) instead of a 51.2MB global round-trip.
// Bs is re-staged with the second weight matrix between stages: LDS stays 48KB.
__global__ __launch_bounds__(256) void k_gemm2(const unsigned short* __restrict__ Ain,
                                               const unsigned short* __restrict__ W2t,
                                               const unsigned short* __restrict__ W1t,
                                               const float* __restrict__ b2,
                                               unsigned short* __restrict__ Cout, int M) {
  __shared__ __align__(16) unsigned short As[64 * 128];
  __shared__ __align__(16) unsigned short Bs[128 * 128];
  const int tid = threadIdx.x;
  const int wid = tid >> 6, lane = tid & 63;
  const int R0 = blockIdx.x * 64;

#pragma unroll
  for (int g = 0; g < 8; g++) {
    int flat = g * 256 + tid;
    int n = flat >> 4, p = flat & 15;
    int l = p ^ (n & 15);
    gl_lds16(W2t + (size_t)n * D + l * 8, &Bs[(size_t)(g * 256 + wid * 64) * 8]);
  }
#pragma unroll
  for (int g = 0; g < 4; g++) {
    int flat = g * 256 + tid;
    int row = flat >> 4, p = flat & 15;
    int l = p ^ (row & 15);
    gl_lds16(Ain + (size_t)(R0 + row) * D + l * 8, &As[(size_t)(g * 256 + wid * 64) * 8]);
  }
  __syncthreads();

  const int wr = wid >> 1, wc = wid & 1;
  const int lm = lane & 15, lq = lane >> 4;
  f32x4 acc[2][4];
#pragma unroll
  for (int i = 0; i < 2; i++)
#pragma unroll
    for (int j = 0; j < 4; j++) acc[i][j] = f32x4{0.f, 0.f, 0.f, 0.f};
#pragma unroll
  for (int kc = 0; kc < 4; kc++) {
    const int pc = (kc * 4 + lq) ^ lm;
    bf16x8 af[2], bfr[4];
#pragma unroll
    for (int i = 0; i < 2; i++)
      af[i] = *(const bf16x8*)&As[(wr * 32 + i * 16 + lm) * D + pc * 8];
#pragma unroll
    for (int j = 0; j < 4; j++)
      bfr[j] = *(const bf16x8*)&Bs[(wc * 64 + j * 16 + lm) * D + pc * 8];
#pragma unroll
    for (int i = 0; i < 2; i++)
#pragma unroll
      for (int j = 0; j < 4; j++)
        acc[i][j] = __builtin_amdgcn_mfma_f32_16x16x32_bf16(af[i], bfr[j], acc[i][j], 0, 0, 0);
  }
  __syncthreads();  // all waves done reading As & Bs

  // re-stage Bs <- W1t (in flight across epilogue1; drained by next barrier)
#pragma unroll
  for (int g = 0; g < 8; g++) {
    int flat = g * 256 + tid;
    int n = flat >> 4, p = flat & 15;
    int l = p ^ (n & 15);
    gl_lds16(W1t + (size_t)n * D + l * 8, &Bs[(size_t)(g * 256 + wid * 64) * 8]);
  }
  // epilogue1: X = relu(acc + b2) -> bf16 into As (same XOR-swizzled layout)
  {
    float bv[4];
#pragma unroll
    for (int j = 0; j < 4; j++) bv[j] = b2[wc * 64 + j * 16 + lm];
#pragma unroll
    for (int i = 0; i < 2; i++) {
#pragma unroll
      for (int reg = 0; reg < 4; reg++) {
        const int row = wr * 32 + i * 16 + lq * 4 + reg;
#pragma unroll
        for (int j = 0; j < 4; j++) {
          const int gc = wc * 64 + j * 16 + lm;
          float v = fmaxf(acc[i][j][reg] + bv[j], 0.f);
          As[row * D + (((gc >> 3) ^ (row & 15)) << 3) + (gc & 7)] = f2bf(v);
        }
      }
    }
  }
  __syncthreads();  // drains gl_lds (vmcnt) + ds_writes

  f32x4 acc2[2][4];
#pragma unroll
  for (int i = 0; i < 2; i++)
#pragma unroll
    for (int j = 0; j < 4; j++) acc2[i][j] = f32x4{0.f, 0.f, 0.f, 0.f};
#pragma unroll
  for (int kc = 0; kc < 4; kc++) {
    const int pc = (kc * 4 + lq) ^ lm;
    bf16x8 af[2], bfr[4];
#pragma unroll
    for (int i = 0; i < 2; i++)
      af[i] = *(const bf16x8*)&As[(wr * 32 + i * 16 + lm) * D + pc * 8];
#pragma unroll
    for (int j = 0; j < 4; j++)
      bfr[j] = *(const bf16x8*)&Bs[(wc * 64 + j * 16 + lm) * D + pc * 8];
#pragma unroll
    for (int i = 0; i < 2; i++)
#pragma unroll
      for (int j = 0; j < 4; j++)
        acc2[i][j] = __builtin_amdgcn_mfma_f32_16x16x32_bf16(af[i], bfr[j], acc2[i][j], 0, 0, 0);
  }
  // epilogue2: Y' bf16 to global (no bias, no relu)
#pragma unroll
  for (int i = 0; i < 2; i++) {
#pragma unroll
    for (int reg = 0; reg < 4; reg++) {
      const int gr = R0 + wr * 32 + i * 16 + lq * 4 + reg;
      if (gr < M) {
#pragma unroll
        for (int j = 0; j < 4; j++) {
          const int gc = wc * 64 + j * 16 + lm;
          Cout[(size_t)gr * D + gc] = f2bf(acc2[i][j][reg]);
        }
      }
    }
  }
}

// ---------------- launch ----------------
// GIN eps=0: out = MLP(x + sum_src x). Linearity: GEMM(W1) first, then aggregate
// (+b1,relu), then fused GEMM pair at layer boundaries. 11 dispatches.
extern "C" void kernel_launch(void* const* d_in, const int* in_sizes, int n_in,
                              void* d_out, int out_size, void* d_ws, size_t ws_size,
                              hipStream_t stream) {
  const float* x  = (const float*)d_in[0];
  const int*   ei = (const int*)d_in[1];
  const float* W1 = (const float*)d_in[2];
  const float* b1 = (const float*)d_in[3];
  const float* W2 = (const float*)d_in[4];
  const float* b2 = (const float*)d_in[5];
  const int N = in_sizes[0] / D;  // 100000
  const int E = in_sizes[1] / 2;  // 1600000
  const int* src = ei;
  const int* dst = ei + E;

  // workspace: Wt (192KB) + 2 bf16 node buffers (N+1 rows) + CSR (~7MB).
  // pairbuf aliases bufB (dead before bufB written).
  char* ws = (char*)d_ws;
  unsigned short* Wt   = (unsigned short*)ws;                 // 6*128*128 bf16
  unsigned short* bufA = Wt + 6 * D * D;
  unsigned short* bufB = bufA + (size_t)(N + 1) * D;
  int* pairbuf = (int*)bufB;
  int* row_ptr = (int*)(bufB + (size_t)(N + 1) * D);
  int* colv    = row_ptr + (N + 1);
  int* bcount  = colv + E;          // 256 ints
  int* bcursor = bcount + 256;      // 256 ints (must follow bcount: zeroed together)
  float* OUT   = (float*)d_out;

  const int CB = (E + CHUNK - 1) / CHUNK;      // 391 chunk blocks
  const int GB = (N + 63) / 64;                // 1563 GEMM tiles
  const int AB = (N + 3) / 4;                  // agg: 4 waves/block, 1 node/wave
  const int BKB = (N + 511) / 512;             // 196 buckets

  k_prep<<<7, 256, 0, stream>>>(W1, W2, Wt, bcount);
  k_bhist<<<CB, 256, 0, stream>>>(dst, E, bcount);
  k_binA<<<CB, 256, 0, stream>>>(src, dst, E, bcount, bcursor, pairbuf);
  k_binB<<<BKB, 256, 0, stream>>>(pairbuf, bcount, colv, row_ptr, N);

  // layer 0 front GEMM: Y0 = x @ W1_0
  k_gemm<true, false><<<GB, 256, 0, stream>>>(x, Wt + 0 * D * D, nullptr, bufA, N, 0);
  k_agg<<<AB, 256, 0, stream>>>(bufA, row_ptr, colv, b1, bufB, N);
  // boundary 0: relu(h0@W2_0+b2_0) @ W1_1
  k_gemm2<<<GB, 256, 0, stream>>>(bufB, Wt + 1 * D * D, Wt + 2 * D * D, b2, bufA, N);
  k_agg<<<AB, 256, 0, stream>>>(bufA, row_ptr, colv, b1 + D, bufB, N);
  // boundary 1
  k_gemm2<<<GB, 256, 0, stream>>>(bufB, Wt + 3 * D * D, Wt + 4 * D * D, b2 + D, bufA, N);
  k_agg<<<AB, 256, 0, stream>>>(bufA, row_ptr, colv, b1 + 2 * D, bufB, N);
  // final GEMM
  k_gemm<false, true><<<GB, 256, 0, stream>>>(bufB, Wt + 5 * D * D, b2 + 2 * D, OUT, N, 0);
  (void)n_in; (void)out_size; (void)ws_size;
}

// Round 6
// 417.936 us; speedup vs baseline: 1.2892x; 1.0064x over previous
//
#include <hip/hip_runtime.h>
#include <hip/hip_bf16.h>

#define D 128  // feature dim (D_IN == D_HID == 128)
#define DD (128 * 128)

typedef float f32x4 __attribute__((ext_vector_type(4)));
typedef __bf16 bf16x8 __attribute__((ext_vector_type(8)));

__device__ __forceinline__ unsigned short f2bf(float f) {
  unsigned int u = __float_as_uint(f);
  u += 0x7fff + ((u >> 16) & 1);  // RNE (no NaN inputs here)
  return (unsigned short)(u >> 16);
}

// async global->LDS, 16B per lane; LDS dest = wave-uniform base + lane*16
__device__ __forceinline__ void gl_lds16(const void* g, void* l) {
  __builtin_amdgcn_global_load_lds(
      (const __attribute__((address_space(1))) unsigned int*)g,
      (__attribute__((address_space(3))) unsigned int*)l, 16, 0, 0);
}

__device__ __forceinline__ int wave_incl_scan(int v, int lane) {
#pragma unroll
  for (int d = 1; d < 64; d <<= 1) {
    int t = __shfl_up(v, d);
    if (lane >= d) v += t;
  }
  return v;
}

// ---------------- CSR build (bucketed; no fine-grained global atomics) ----------------
#define NBK 196      // ceil(100000 / 512) buckets of 512 nodes
#define CHUNK 4096

__global__ __launch_bounds__(256) void k_bhist(const int* __restrict__ dst, int E,
                                               int* __restrict__ bcount) {
  __shared__ int cnt[NBK];
  const int tid = threadIdx.x;
  for (int i = tid; i < NBK; i += 256) cnt[i] = 0;
  __syncthreads();
  const int e0 = blockIdx.x * CHUNK;
  const int emax = min(e0 + CHUNK, E);
  for (int e = e0 + tid; e < emax; e += 256)
    atomicAdd(&cnt[((unsigned)dst[e]) >> 9], 1);
  __syncthreads();
  for (int i = tid; i < NBK; i += 256)
    if (cnt[i]) atomicAdd(&bcount[i], cnt[i]);
}

__global__ __launch_bounds__(256) void k_binA(const int* __restrict__ src,
                                              const int* __restrict__ dst, int E,
                                              const int* __restrict__ bcount,
                                              int* __restrict__ bcursor,
                                              int* __restrict__ pairbuf) {
  __shared__ int cnt[NBK];
  __shared__ int base[NBK];
  __shared__ int bb[NBK];  // local exclusive scan of bcount
  __shared__ int ws4[4];
  const int tid = threadIdx.x;
  const int e0 = blockIdx.x * CHUNK;
  const int emax = min(e0 + CHUNK, E);
  for (int i = tid; i < NBK; i += 256) cnt[i] = 0;
  {
    int lane = tid & 63, w = tid >> 6;
    int v = (tid < NBK) ? bcount[tid] : 0;
    int s = wave_incl_scan(v, lane);
    if (lane == 63) ws4[w] = s;
    __syncthreads();
    if (tid < NBK) {
      int off = 0;
      for (int k = 0; k < w; k++) off += ws4[k];
      bb[tid] = off + s - v;
    }
  }
  __syncthreads();
  for (int e = e0 + tid; e < emax; e += 256)
    atomicAdd(&cnt[((unsigned)dst[e]) >> 9], 1);
  __syncthreads();
  for (int i = tid; i < NBK; i += 256) {
    int c = cnt[i];
    int b = 0;
    if (c) b = atomicAdd(&bcursor[i], c) + bb[i];
    base[i] = b;
    cnt[i] = 0;
  }
  __syncthreads();
  for (int e = e0 + tid; e < emax; e += 256) {
    int d = dst[e];
    int bk = ((unsigned)d) >> 9;
    int pos = base[bk] + atomicAdd(&cnt[bk], 1);
    pairbuf[pos] = (src[e] << 9) | (d & 511);  // src<2^17, fits in 26 bits
  }
}

#define SEG_CAP 12800
__global__ __launch_bounds__(256) void k_binB(const int* __restrict__ pairbuf,
                                              const int* __restrict__ bcount,
                                              int* __restrict__ col,
                                              int* __restrict__ row_ptr, int N) {
  __shared__ int sdeg[512];
  __shared__ int rpl[512];
  __shared__ int cur[512];
  __shared__ int wsum[4];
  __shared__ int wsum2[4];
  __shared__ int stage[SEG_CAP];
  const int tid = threadIdx.x;
  const int lane = tid & 63, wid = tid >> 6;
  const int node0 = blockIdx.x << 9;
  const int nn = min(512, N - node0);
  {
    int vv = (tid < (int)blockIdx.x) ? bcount[tid] : 0;
    vv += __shfl_down(vv, 32); vv += __shfl_down(vv, 16);
    vv += __shfl_down(vv, 8);  vv += __shfl_down(vv, 4);
    vv += __shfl_down(vv, 2);  vv += __shfl_down(vv, 1);
    if (lane == 0) wsum2[wid] = vv;
  }
  for (int i = tid; i < 512; i += 256) { sdeg[i] = 0; cur[i] = 0; }
  __syncthreads();
  const int start = wsum2[0] + wsum2[1] + wsum2[2] + wsum2[3];
  const int end = start + bcount[blockIdx.x];
  const int sz = end - start;
  for (int i = tid; i < sz; i += 256)
    atomicAdd(&sdeg[pairbuf[start + i] & 511], 1);
  __syncthreads();
  int a = sdeg[2 * tid], b = sdeg[2 * tid + 1];
  int v = a + b;
  int s = wave_incl_scan(v, lane);
  if (lane == 63) wsum[wid] = s;
  __syncthreads();
  int off = 0;
  for (int k = 0; k < wid; k++) off += wsum[k];
  int e0l = off + s - v;
  rpl[2 * tid] = e0l;
  rpl[2 * tid + 1] = e0l + a;
  __syncthreads();
  for (int i = tid; i < nn; i += 256) row_ptr[node0 + i] = start + rpl[i];
  if (blockIdx.x == gridDim.x - 1 && tid == 0) row_ptr[N] = end;
  for (int i = tid; i < sz; i += 256) {
    int pk = pairbuf[start + i];
    int d = pk & 511;
    int pos = rpl[d] + atomicAdd(&cur[d], 1);
    if (pos < SEG_CAP) stage[pos] = (int)(((unsigned)pk) >> 9);
  }
  __syncthreads();
  for (int i = tid; i < sz; i += 256) col[start + i] = stage[i];
}

// ---- weight prep + zero bcount/bcursor/barrier (516 ints, strided — R2 lesson) ----
__global__ void k_prep(const float* __restrict__ W1, const float* __restrict__ W2,
                       unsigned short* __restrict__ Wt, int* __restrict__ bcount) {
  int b = blockIdx.x;
  if (b < 6) {
    const float* W = (b & 1) ? (W2 + (size_t)(b >> 1) * DD) : (W1 + (size_t)(b >> 1) * DD);
    unsigned short* O = Wt + (size_t)b * DD;
    for (int i = threadIdx.x; i < DD; i += 256) {
      int n = i >> 7, k = i & 127;
      O[n * D + k] = f2bf(W[k * D + n]);
    }
  } else {
    for (int i = threadIdx.x; i < 516; i += 256) bcount[i] = 0;
  }
}

// ---------------- software grid barrier (device-scope; cross-XCD-safe) ----------------
// Only used under hipLaunchCooperativeKernel (runtime-guaranteed co-residency).
__device__ __forceinline__ void gsync(int* cnt, int* gen) {
  __syncthreads();
  if (threadIdx.x == 0) {
    int g = __hip_atomic_load(gen, __ATOMIC_RELAXED, __HIP_MEMORY_SCOPE_AGENT);
    __threadfence();  // release: publish this block's writes device-wide
    if (__hip_atomic_fetch_add(cnt, 1, __ATOMIC_ACQ_REL, __HIP_MEMORY_SCOPE_AGENT) ==
        (int)gridDim.x - 1) {
      __hip_atomic_store(cnt, 0, __ATOMIC_RELAXED, __HIP_MEMORY_SCOPE_AGENT);
      __hip_atomic_fetch_add(gen, 1, __ATOMIC_RELEASE, __HIP_MEMORY_SCOPE_AGENT);
    } else {
      while (__hip_atomic_load(gen, __ATOMIC_ACQUIRE, __HIP_MEMORY_SCOPE_AGENT) == g)
        __builtin_amdgcn_s_sleep(2);
    }
    __threadfence();  // acquire: invalidate stale cache before next phase reads
  }
  __syncthreads();
}

// ---------------- mega-kernel tile helpers (64-row tile, B in 64-col halves) ----------
__device__ __forceinline__ void stage_w_half(const unsigned short* __restrict__ W, int n0,
                                             unsigned short* Bs, int tid) {
#pragma unroll
  for (int g = 0; g < 4; g++) {
    int flat = g * 256 + tid;
    int n = flat >> 4, p = flat & 15, l = p ^ (n & 15);
    gl_lds16(W + (size_t)(n0 + n) * D + l * 8, &Bs[(size_t)(g * 256 + (tid >> 6) * 64) * 8]);
  }
}

__device__ __forceinline__ void stage_a_bf(const unsigned short* __restrict__ A, int R0,
                                           unsigned short* As, int tid) {
#pragma unroll
  for (int g = 0; g < 4; g++) {
    int flat = g * 256 + tid;
    int row = flat >> 4, p = flat & 15, l = p ^ (row & 15);
    // rows >= N read garbage from adjacent ws regions (allocated; outputs unstored)
    gl_lds16(A + (size_t)(R0 + row) * D + l * 8,
             &As[(size_t)(g * 256 + (tid >> 6) * 64) * 8]);
  }
}

// wave wid covers rows [wid*16, wid*16+16), cols = the 64 staged in Bs
__device__ __forceinline__ void mma_half(const unsigned short* As, const unsigned short* Bs,
                                         int wid, int lm, int lq, f32x4 a[4]) {
#pragma unroll
  for (int kc = 0; kc < 4; kc++) {
    const int pc = (kc * 4 + lq) ^ lm;
    bf16x8 af = *(const bf16x8*)&As[(wid * 16 + lm) * D + pc * 8];
#pragma unroll
    for (int j = 0; j < 4; j++) {
      bf16x8 bf = *(const bf16x8*)&Bs[(j * 16 + lm) * D + pc * 8];
      a[j] = __builtin_amdgcn_mfma_f32_16x16x32_bf16(af, bf, a[j], 0, 0, 0);
    }
  }
}

// ---------------- the persistent mega-kernel (cooperative launch only) ----------------
// P0: bufA = x @ W1_0 | per layer L: agg(bufA->bufB,+b1,relu) | L<2: bufA =
// relu(bufB@W2^T+b2)@W1n^T | L=2: OUT = bufB@W2^T + b2 (fp32).
// LDS 32KB -> 5 blocks/CU -> agg phases run at 20 waves/CU (~= R4's 21; R3 lesson).
__global__ __launch_bounds__(256, 5) void k_mega(
    const float* __restrict__ x, unsigned short* __restrict__ bufA,
    unsigned short* __restrict__ bufB, const int* __restrict__ row_ptr,
    const int* __restrict__ col, const unsigned short* __restrict__ Wt,
    const float* __restrict__ b1, const float* __restrict__ b2,
    float* __restrict__ OUT, int N, int* __restrict__ bar) {
  __shared__ __align__(16) unsigned short As[64 * D];
  __shared__ __align__(16) unsigned short Bs[64 * D];
  const int tid = threadIdx.x, wid = tid >> 6, lane = tid & 63;
  const int lm = lane & 15, lq = lane >> 4;
  const int nT = (N + 63) >> 6;
  int* cnt = bar;
  int* gen = bar + 1;

  // ---- P0: gemm0 (fp32 A in, bf16 out, no bias/relu) ----
  for (int t = blockIdx.x; t < nT; t += gridDim.x) {
    const int R0 = t << 6;
#pragma unroll
    for (int g = 0; g < 4; g++) {
      int flat = g * 256 + tid, row = flat >> 4, p = flat & 15, l = p ^ (row & 15);
      float4 q0 = make_float4(0.f, 0.f, 0.f, 0.f), q1 = q0;
      if (R0 + row < N) {
        q0 = *(const float4*)(x + (size_t)(R0 + row) * D + l * 8);
        q1 = *(const float4*)(x + (size_t)(R0 + row) * D + l * 8 + 4);
      }
      ushort4 v0, v1;
      v0.x = f2bf(q0.x); v0.y = f2bf(q0.y); v0.z = f2bf(q0.z); v0.w = f2bf(q0.w);
      v1.x = f2bf(q1.x); v1.y = f2bf(q1.y); v1.z = f2bf(q1.z); v1.w = f2bf(q1.w);
      *(ushort4*)&As[row * D + p * 8] = v0;
      *(ushort4*)&As[row * D + p * 8 + 4] = v1;
    }
#pragma unroll
    for (int h = 0; h < 2; h++) {
      stage_w_half(Wt, h * 64, Bs, tid);
      __syncthreads();
      f32x4 a[4];
#pragma unroll
      for (int j = 0; j < 4; j++) a[j] = f32x4{0.f, 0.f, 0.f, 0.f};
      mma_half(As, Bs, wid, lm, lq, a);
#pragma unroll
      for (int j = 0; j < 4; j++)
#pragma unroll
        for (int r = 0; r < 4; r++) {
          int gr = R0 + wid * 16 + lq * 4 + r;
          if (gr < N) bufA[(size_t)gr * D + h * 64 + j * 16 + lm] = f2bf(a[j][r]);
        }
      __syncthreads();
    }
  }
  gsync(cnt, gen);

  // ---- 3 layers ----
#pragma unroll 1
  for (int L = 0; L < 3; L++) {
    {  // aggregation: bufA -> bufB (v1 body; no returns — gsync must be reached)
      const unsigned int* Yu = (const unsigned int*)bufA;
      unsigned int* Hu = (unsigned int*)bufB;
      const float2 bv = ((const float2*)(b1 + (size_t)L * D))[lane];
      const int nw = gridDim.x << 2;
      for (int node = (blockIdx.x << 2) + wid; node < N; node += nw) {
        unsigned int sv = Yu[(size_t)node * 64 + lane];
        float ax = bv.x + __uint_as_float(sv << 16);
        float ay = bv.y + __uint_as_float(sv & 0xffff0000u);
        int rs = row_ptr[node], re = row_ptr[node + 1];
        int dcap = min(re - rs, 64);
        int cv = (lane < dcap) ? col[rs + lane] : 0;
        int j = 0;
        for (; j + 8 <= dcap; j += 8) {
          int s0 = __shfl(cv, j + 0), s1 = __shfl(cv, j + 1);
          int s2 = __shfl(cv, j + 2), s3 = __shfl(cv, j + 3);
          int s4 = __shfl(cv, j + 4), s5 = __shfl(cv, j + 5);
          int s6 = __shfl(cv, j + 6), s7 = __shfl(cv, j + 7);
          unsigned int v0 = Yu[(size_t)s0 * 64 + lane];
          unsigned int v1 = Yu[(size_t)s1 * 64 + lane];
          unsigned int v2 = Yu[(size_t)s2 * 64 + lane];
          unsigned int v3 = Yu[(size_t)s3 * 64 + lane];
          unsigned int v4 = Yu[(size_t)s4 * 64 + lane];
          unsigned int v5 = Yu[(size_t)s5 * 64 + lane];
          unsigned int v6 = Yu[(size_t)s6 * 64 + lane];
          unsigned int v7 = Yu[(size_t)s7 * 64 + lane];
          ax += ((__uint_as_float(v0 << 16) + __uint_as_float(v1 << 16)) +
                 (__uint_as_float(v2 << 16) + __uint_as_float(v3 << 16))) +
                ((__uint_as_float(v4 << 16) + __uint_as_float(v5 << 16)) +
                 (__uint_as_float(v6 << 16) + __uint_as_float(v7 << 16)));
          ay += ((__uint_as_float(v0 & 0xffff0000u) + __uint_as_float(v1 & 0xffff0000u)) +
                 (__uint_as_float(v2 & 0xffff0000u) + __uint_as_float(v3 & 0xffff0000u))) +
                ((__uint_as_float(v4 & 0xffff0000u) + __uint_as_float(v5 & 0xffff0000u)) +
                 (__uint_as_float(v6 & 0xffff0000u) + __uint_as_float(v7 & 0xffff0000u)));
        }
        for (; j < dcap; j++) {
          int s = __shfl(cv, j);
          unsigned int v = Yu[(size_t)s * 64 + lane];
          ax += __uint_as_float(v << 16);
          ay += __uint_as_float(v & 0xffff0000u);
        }
        for (int t2 = rs + 64; t2 < re; t2++) {  // deg>64 correctness net
          unsigned int v = Yu[(size_t)col[t2] * 64 + lane];
          ax += __uint_as_float(v << 16);
          ay += __uint_as_float(v & 0xffff0000u);
        }
        Hu[(size_t)node * 64 + lane] =
            ((unsigned int)f2bf(fmaxf(ay, 0.f)) << 16) | f2bf(fmaxf(ax, 0.f));
      }
    }
    gsync(cnt, gen);

    if (L < 2) {
      // fused GEMM pair: bufA = relu(bufB @ Wa^T + b2) @ Wb^T
      const unsigned short* Wa = Wt + (size_t)(2 * L + 1) * DD;
      const unsigned short* Wb = Wt + (size_t)(2 * L + 2) * DD;
      const float* bb = b2 + (size_t)L * D;
      for (int t = blockIdx.x; t < nT; t += gridDim.x) {
        const int R0 = t << 6;
        stage_a_bf(bufB, R0, As, tid);
        f32x4 acc[2][4];
#pragma unroll
        for (int h = 0; h < 2; h++) {
          stage_w_half(Wa, h * 64, Bs, tid);
          __syncthreads();  // drains As+Bs gl_lds
#pragma unroll
          for (int j = 0; j < 4; j++) acc[h][j] = f32x4{0.f, 0.f, 0.f, 0.f};
          mma_half(As, Bs, wid, lm, lq, acc[h]);
          __syncthreads();  // all waves done with this Bs half (As kept)
        }
        // X' = relu(acc + b2) -> As (swizzled); each wave rewrites only its own 16 rows
#pragma unroll
        for (int h = 0; h < 2; h++)
#pragma unroll
          for (int j = 0; j < 4; j++)
#pragma unroll
            for (int r = 0; r < 4; r++) {
              int row = wid * 16 + lq * 4 + r;
              int gc = h * 64 + j * 16 + lm;
              float v = fmaxf(acc[h][j][r] + bb[gc], 0.f);
              As[row * D + (((gc >> 3) ^ (row & 15)) << 3) + (gc & 7)] = f2bf(v);
            }
        __syncthreads();
#pragma unroll
        for (int h = 0; h < 2; h++) {
          stage_w_half(Wb, h * 64, Bs, tid);
          __syncthreads();
          f32x4 c[4];
#pragma unroll
          for (int j = 0; j < 4; j++) c[j] = f32x4{0.f, 0.f, 0.f, 0.f};
          mma_half(As, Bs, wid, lm, lq, c);
#pragma unroll
          for (int j = 0; j < 4; j++)
#pragma unroll
            for (int r = 0; r < 4; r++) {
              int gr = R0 + wid * 16 + lq * 4 + r;
              if (gr < N) bufA[(size_t)gr * D + h * 64 + j * 16 + lm] = f2bf(c[j][r]);
            }
          __syncthreads();
        }
      }
      gsync(cnt, gen);
    } else {
      // final GEMM: OUT = bufB @ W2_2^T + b2_2 (fp32)
      const unsigned short* Wa = Wt + (size_t)5 * DD;
      const float* bb = b2 + (size_t)2 * D;
      for (int t = blockIdx.x; t < nT; t += gridDim.x) {
        const int R0 = t << 6;
        stage_a_bf(bufB, R0, As, tid);
#pragma unroll
        for (int h = 0; h < 2; h++) {
          stage_w_half(Wa, h * 64, Bs, tid);
          __syncthreads();
          f32x4 c[4];
#pragma unroll
          for (int j = 0; j < 4; j++) c[j] = f32x4{0.f, 0.f, 0.f, 0.f};
          mma_half(As, Bs, wid, lm, lq, c);
#pragma unroll
          for (int j = 0; j < 4; j++)
#pragma unroll
            for (int r = 0; r < 4; r++) {
              int gr = R0 + wid * 16 + lq * 4 + r;
              if (gr < N)
                OUT[(size_t)gr * D + h * 64 + j * 16 + lm] = c[j][r] + bb[h * 64 + j * 16 + lm];
            }
          __syncthreads();
        }
      }
      // no trailing gsync: kernel end
    }
  }
}

// ---------------- fallback kernels (proven R4 path) ----------------
__global__ __launch_bounds__(256) void k_agg(const unsigned short* __restrict__ Y,
                                             const int* __restrict__ row_ptr,
                                             const int* __restrict__ col,
                                             const float* __restrict__ bias,
                                             unsigned short* __restrict__ H, int N) {
  int wid = (blockIdx.x * 256 + threadIdx.x) >> 6;
  int lane = threadIdx.x & 63;
  if (wid >= N) return;
  const unsigned int* Yu = (const unsigned int*)Y;
  unsigned int sv = Yu[(size_t)wid * 64 + lane];
  float2 bv = ((const float2*)bias)[lane];
  float ax = bv.x + __uint_as_float(sv << 16);
  float ay = bv.y + __uint_as_float(sv & 0xffff0000u);
  int rs = row_ptr[wid], re = row_ptr[wid + 1];
  int dcap = min(re - rs, 64);
  int cv = (lane < dcap) ? col[rs + lane] : 0;
  int j = 0;
  for (; j + 8 <= dcap; j += 8) {
    int s0 = __shfl(cv, j + 0), s1 = __shfl(cv, j + 1);
    int s2 = __shfl(cv, j + 2), s3 = __shfl(cv, j + 3);
    int s4 = __shfl(cv, j + 4), s5 = __shfl(cv, j + 5);
    int s6 = __shfl(cv, j + 6), s7 = __shfl(cv, j + 7);
    unsigned int v0 = Yu[(size_t)s0 * 64 + lane];
    unsigned int v1 = Yu[(size_t)s1 * 64 + lane];
    unsigned int v2 = Yu[(size_t)s2 * 64 + lane];
    unsigned int v3 = Yu[(size_t)s3 * 64 + lane];
    unsigned int v4 = Yu[(size_t)s4 * 64 + lane];
    unsigned int v5 = Yu[(size_t)s5 * 64 + lane];
    unsigned int v6 = Yu[(size_t)s6 * 64 + lane];
    unsigned int v7 = Yu[(size_t)s7 * 64 + lane];
    ax += ((__uint_as_float(v0 << 16) + __uint_as_float(v1 << 16)) +
           (__uint_as_float(v2 << 16) + __uint_as_float(v3 << 16))) +
          ((__uint_as_float(v4 << 16) + __uint_as_float(v5 << 16)) +
           (__uint_as_float(v6 << 16) + __uint_as_float(v7 << 16)));
    ay += ((__uint_as_float(v0 & 0xffff0000u) + __uint_as_float(v1 & 0xffff0000u)) +
           (__uint_as_float(v2 & 0xffff0000u) + __uint_as_float(v3 & 0xffff0000u))) +
          ((__uint_as_float(v4 & 0xffff0000u) + __uint_as_float(v5 & 0xffff0000u)) +
           (__uint_as_float(v6 & 0xffff0000u) + __uint_as_float(v7 & 0xffff0000u)));
  }
  for (; j < dcap; j++) {
    int s = __shfl(cv, j);
    unsigned int v = Yu[(size_t)s * 64 + lane];
    ax += __uint_as_float(v << 16);
    ay += __uint_as_float(v & 0xffff0000u);
  }
  for (int t = rs + 64; t < re; t++) {
    unsigned int v = Yu[(size_t)col[t] * 64 + lane];
    ax += __uint_as_float(v << 16);
    ay += __uint_as_float(v & 0xffff0000u);
  }
  ax = fmaxf(ax, 0.f);
  ay = fmaxf(ay, 0.f);
  ((unsigned int*)H)[(size_t)wid * 64 + lane] =
      ((unsigned int)f2bf(ay) << 16) | f2bf(ax);
}

template <bool A_FP32, bool OUT_FP32>
__global__ __launch_bounds__(256) void k_gemm(const void* __restrict__ Ain,
                                              const unsigned short* __restrict__ Wt,
                                              const float* __restrict__ bias,
                                              void* __restrict__ Cout, int M, int relu) {
  __shared__ __align__(16) unsigned short As[64 * 128];
  __shared__ __align__(16) unsigned short Bs[128 * 128];
  const int tid = threadIdx.x;
  const int wid = tid >> 6, lane = tid & 63;
  const int R0 = blockIdx.x * 64;
#pragma unroll
  for (int g = 0; g < 8; g++) {
    int flat = g * 256 + tid;
    int n = flat >> 4, p = flat & 15;
    int l = p ^ (n & 15);
    gl_lds16(Wt + (size_t)n * D + l * 8, &Bs[(size_t)(g * 256 + wid * 64) * 8]);
  }
  if (A_FP32) {
    const float* A = (const float*)Ain;
#pragma unroll
    for (int g = 0; g < 4; g++) {
      int flat = g * 256 + tid;
      int row = flat >> 4, p = flat & 15;
      int l = p ^ (row & 15);
      float4 a0 = make_float4(0.f, 0.f, 0.f, 0.f), a1 = a0;
      if (R0 + row < M) {
        a0 = *(const float4*)(A + (size_t)(R0 + row) * D + l * 8);
        a1 = *(const float4*)(A + (size_t)(R0 + row) * D + l * 8 + 4);
      }
      ushort4 v0, v1;
      v0.x = f2bf(a0.x); v0.y = f2bf(a0.y); v0.z = f2bf(a0.z); v0.w = f2bf(a0.w);
      v1.x = f2bf(a1.x); v1.y = f2bf(a1.y); v1.z = f2bf(a1.z); v1.w = f2bf(a1.w);
      *(ushort4*)&As[row * D + p * 8] = v0;
      *(ushort4*)&As[row * D + p * 8 + 4] = v1;
    }
  } else {
    const unsigned short* A = (const unsigned short*)Ain;
#pragma unroll
    for (int g = 0; g < 4; g++) {
      int flat = g * 256 + tid;
      int row = flat >> 4, p = flat & 15;
      int l = p ^ (row & 15);
      gl_lds16(A + (size_t)(R0 + row) * D + l * 8, &As[(size_t)(g * 256 + wid * 64) * 8]);
    }
  }
  __syncthreads();
  const int wr = wid >> 1, wc = wid & 1;
  const int lm = lane & 15, lq = lane >> 4;
  f32x4 acc[2][4];
#pragma unroll
  for (int i = 0; i < 2; i++)
#pragma unroll
    for (int j = 0; j < 4; j++) acc[i][j] = f32x4{0.f, 0.f, 0.f, 0.f};
#pragma unroll
  for (int kc = 0; kc < 4; kc++) {
    const int pc = (kc * 4 + lq) ^ lm;
    bf16x8 af[2], bfr[4];
#pragma unroll
    for (int i = 0; i < 2; i++)
      af[i] = *(const bf16x8*)&As[(wr * 32 + i * 16 + lm) * D + pc * 8];
#pragma unroll
    for (int j = 0; j < 4; j++)
      bfr[j] = *(const bf16x8*)&Bs[(wc * 64 + j * 16 + lm) * D + pc * 8];
#pragma unroll
    for (int i = 0; i < 2; i++)
#pragma unroll
      for (int j = 0; j < 4; j++)
        acc[i][j] = __builtin_amdgcn_mfma_f32_16x16x32_bf16(af[i], bfr[j], acc[i][j], 0, 0, 0);
  }
  float bv[4];
#pragma unroll
  for (int j = 0; j < 4; j++) bv[j] = bias ? bias[wc * 64 + j * 16 + lm] : 0.f;
#pragma unroll
  for (int i = 0; i < 2; i++) {
#pragma unroll
    for (int reg = 0; reg < 4; reg++) {
      const int gr = R0 + wr * 32 + i * 16 + lq * 4 + reg;
      if (gr < M) {
#pragma unroll
        for (int j = 0; j < 4; j++) {
          const int gc = wc * 64 + j * 16 + lm;
          float v = acc[i][j][reg] + bv[j];
          if (relu) v = fmaxf(v, 0.f);
          if (OUT_FP32)
            ((float*)Cout)[(size_t)gr * D + gc] = v;
          else
            ((unsigned short*)Cout)[(size_t)gr * D + gc] = f2bf(v);
        }
      }
    }
  }
}

__global__ __launch_bounds__(256) void k_gemm2(const unsigned short* __restrict__ Ain,
                                               const unsigned short* __restrict__ W2t,
                                               const unsigned short* __restrict__ W1t,
                                               const float* __restrict__ b2,
                                               unsigned short* __restrict__ Cout, int M) {
  __shared__ __align__(16) unsigned short As[64 * 128];
  __shared__ __align__(16) unsigned short Bs[128 * 128];
  const int tid = threadIdx.x;
  const int wid = tid >> 6, lane = tid & 63;
  const int R0 = blockIdx.x * 64;
#pragma unroll
  for (int g = 0; g < 8; g++) {
    int flat = g * 256 + tid;
    int n = flat >> 4, p = flat & 15;
    int l = p ^ (n & 15);
    gl_lds16(W2t + (size_t)n * D + l * 8, &Bs[(size_t)(g * 256 + wid * 64) * 8]);
  }
#pragma unroll
  for (int g = 0; g < 4; g++) {
    int flat = g * 256 + tid;
    int row = flat >> 4, p = flat & 15;
    int l = p ^ (row & 15);
    gl_lds16(Ain + (size_t)(R0 + row) * D + l * 8, &As[(size_t)(g * 256 + wid * 64) * 8]);
  }
  __syncthreads();
  const int wr = wid >> 1, wc = wid & 1;
  const int lm = lane & 15, lq = lane >> 4;
  f32x4 acc[2][4];
#pragma unroll
  for (int i = 0; i < 2; i++)
#pragma unroll
    for (int j = 0; j < 4; j++) acc[i][j] = f32x4{0.f, 0.f, 0.f, 0.f};
#pragma unroll
  for (int kc = 0; kc < 4; kc++) {
    const int pc = (kc * 4 + lq) ^ lm;
    bf16x8 af[2], bfr[4];
#pragma unroll
    for (int i = 0; i < 2; i++)
      af[i] = *(const bf16x8*)&As[(wr * 32 + i * 16 + lm) * D + pc * 8];
#pragma unroll
    for (int j = 0; j < 4; j++)
      bfr[j] = *(const bf16x8*)&Bs[(wc * 64 + j * 16 + lm) * D + pc * 8];
#pragma unroll
    for (int i = 0; i < 2; i++)
#pragma unroll
      for (int j = 0; j < 4; j++)
        acc[i][j] = __builtin_amdgcn_mfma_f32_16x16x32_bf16(af[i], bfr[j], acc[i][j], 0, 0, 0);
  }
  __syncthreads();
#pragma unroll
  for (int g = 0; g < 8; g++) {
    int flat = g * 256 + tid;
    int n = flat >> 4, p = flat & 15;
    int l = p ^ (n & 15);
    gl_lds16(W1t + (size_t)n * D + l * 8, &Bs[(size_t)(g * 256 + wid * 64) * 8]);
  }
  {
    float bv[4];
#pragma unroll
    for (int j = 0; j < 4; j++) bv[j] = b2[wc * 64 + j * 16 + lm];
#pragma unroll
    for (int i = 0; i < 2; i++) {
#pragma unroll
      for (int reg = 0; reg < 4; reg++) {
        const int row = wr * 32 + i * 16 + lq * 4 + reg;
#pragma unroll
        for (int j = 0; j < 4; j++) {
          const int gc = wc * 64 + j * 16 + lm;
          float v = fmaxf(acc[i][j][reg] + bv[j], 0.f);
          As[row * D + (((gc >> 3) ^ (row & 15)) << 3) + (gc & 7)] = f2bf(v);
        }
      }
    }
  }
  __syncthreads();
  f32x4 acc2[2][4];
#pragma unroll
  for (int i = 0; i < 2; i++)
#pragma unroll
    for (int j = 0; j < 4; j++) acc2[i][j] = f32x4{0.f, 0.f, 0.f, 0.f};
#pragma unroll
  for (int kc = 0; kc < 4; kc++) {
    const int pc = (kc * 4 + lq) ^ lm;
    bf16x8 af[2], bfr[4];
#pragma unroll
    for (int i = 0; i < 2; i++)
      af[i] = *(const bf16x8*)&As[(wr * 32 + i * 16 + lm) * D + pc * 8];
#pragma unroll
    for (int j = 0; j < 4; j++)
      bfr[j] = *(const bf16x8*)&Bs[(wc * 64 + j * 16 + lm) * D + pc * 8];
#pragma unroll
    for (int i = 0; i < 2; i++)
#pragma unroll
      for (int j = 0; j < 4; j++)
        acc2[i][j] = __builtin_amdgcn_mfma_f32_16x16x32_bf16(af[i], bfr[j], acc2[i][j], 0, 0, 0);
  }
#pragma unroll
  for (int i = 0; i < 2; i++) {
#pragma unroll
    for (int reg = 0; reg < 4; reg++) {
      const int gr = R0 + wr * 32 + i * 16 + lq * 4 + reg;
      if (gr < M) {
#pragma unroll
        for (int j = 0; j < 4; j++) {
          const int gc = wc * 64 + j * 16 + lm;
          Cout[(size_t)gr * D + gc] = f2bf(acc2[i][j][reg]);
        }
      }
    }
  }
}

// ---------------- launch ----------------
extern "C" void kernel_launch(void* const* d_in, const int* in_sizes, int n_in,
                              void* d_out, int out_size, void* d_ws, size_t ws_size,
                              hipStream_t stream) {
  const float* x  = (const float*)d_in[0];
  const int*   ei = (const int*)d_in[1];
  const float* W1 = (const float*)d_in[2];
  const float* b1 = (const float*)d_in[3];
  const float* W2 = (const float*)d_in[4];
  const float* b2 = (const float*)d_in[5];
  const int N = in_sizes[0] / D;  // 100000
  const int E = in_sizes[1] / 2;  // 1600000
  const int* src = ei;
  const int* dst = ei + E;

  char* ws = (char*)d_ws;
  unsigned short* Wt   = (unsigned short*)ws;                 // 6*128*128 bf16
  unsigned short* bufA = Wt + 6 * DD;
  unsigned short* bufB = bufA + (size_t)(N + 1) * D;
  int* pairbuf = (int*)bufB;  // aliases bufB: dead before bufB first written
  int* row_ptr = (int*)(bufB + (size_t)(N + 1) * D);
  int* colv    = row_ptr + (N + 1);
  int* bcount  = colv + E;          // 256 ints
  int* bcursor = bcount + 256;      // 256 ints
  int* bar     = bcount + 512;      // 2 ints (grid barrier; zeroed by k_prep)
  float* OUT   = (float*)d_out;

  const int CB = (E + CHUNK - 1) / CHUNK;
  const int GB = (N + 63) / 64;
  const int AB = (N + 3) / 4;
  const int BKB = (N + 511) / 512;

  k_prep<<<7, 256, 0, stream>>>(W1, W2, Wt, bcount);
  k_bhist<<<CB, 256, 0, stream>>>(dst, E, bcount);
  k_binA<<<CB, 256, 0, stream>>>(src, dst, E, bcount, bcursor, pairbuf);
  k_binB<<<BKB, 256, 0, stream>>>(pairbuf, bcount, colv, row_ptr, N);

  // ---- mega path: COOPERATIVE launch only (runtime-validated co-residency).
  // R5 lesson: a plain launch + manual capacity arithmetic risks a spin-deadlock if
  // even one block isn't resident. Cooperative launch either guarantees residency or
  // fails cleanly -> fallback. Decision made from return codes; no hang possible.
  bool mega_ok = false;
  int nb = 0;
  hipError_t qe = hipOccupancyMaxActiveBlocksPerMultiprocessor(&nb, k_mega, 256, 0);
  if (qe == hipSuccess && nb >= 4) {
    int Nv = N;
    const int grid = (nb < 5 ? nb : 5) * 256;
    void* args[] = {(void*)&x,  (void*)&bufA, (void*)&bufB, (void*)&row_ptr,
                    (void*)&colv, (void*)&Wt, (void*)&b1,   (void*)&b2,
                    (void*)&OUT, (void*)&Nv,  (void*)&bar};
    hipError_t ce = hipLaunchCooperativeKernel(k_mega, dim3(grid), dim3(256), args, 0, stream);
    mega_ok = (ce == hipSuccess);
    if (!mega_ok) (void)hipGetLastError();  // clear sticky error before fallback
  }
  if (!mega_ok) {
    // fallback: proven R4 multi-dispatch path (~420us)
    k_gemm<true, false><<<GB, 256, 0, stream>>>(x, Wt + 0 * DD, nullptr, bufA, N, 0);
    k_agg<<<AB, 256, 0, stream>>>(bufA, row_ptr, colv, b1, bufB, N);
    k_gemm2<<<GB, 256, 0, stream>>>(bufB, Wt + 1 * DD, Wt + 2 * DD, b2, bufA, N);
    k_agg<<<AB, 256, 0, stream>>>(bufA, row_ptr, colv, b1 + D, bufB, N);
    k_gemm2<<<GB, 256, 0, stream>>>(bufB, Wt + 3 * DD, Wt + 4 * DD, b2 + D, bufA, N);
    k_agg<<<AB, 256, 0, stream>>>(bufA, row_ptr, colv, b1 + 2 * D, bufB, N);
    k_gemm<false, true><<<GB, 256, 0, stream>>>(bufB, Wt + 5 * DD, b2 + 2 * D, OUT, N, 0);
  }
  (void)n_in; (void)out_size; (void)ws_size;
}